// Round 1
// baseline (513.530 us; speedup 1.0000x reference)
//
#include <hip/hip_runtime.h>
#include <stdint.h>

#define TT 2048
#define HH 1024
#define II 4096
#define EE 8

typedef __attribute__((ext_vector_type(4))) float floatx4;
typedef __attribute__((ext_vector_type(8))) __bf16 bf16x8;

// round-to-nearest-even fp32 -> bf16 (bits)
__device__ __forceinline__ unsigned short f2bf(float f) {
  union { float f; unsigned u; } v; v.f = f;
  return (unsigned short)((v.u + 0x7FFFu + ((v.u >> 16) & 1u)) >> 16);
}

// async global->LDS, 16 bytes per lane; LDS dest must be wave-uniform base + lane*16
__device__ __forceinline__ void async_ld16(const void* g, void* l) {
  __builtin_amdgcn_global_load_lds(
      (__attribute__((address_space(1))) void*)g,
      (__attribute__((address_space(3))) void*)l, 16, 0, 0);
}

// ---------------- gating: fp32 logits, softmax top-2, renorm; emit x_bf16 ----
__global__ __launch_bounds__(256) void k_gating(
    const float* __restrict__ x, const float* __restrict__ gw,
    unsigned short* __restrict__ xb, int* __restrict__ sel_e,
    float* __restrict__ sel_w, int* __restrict__ counts) {
  int t = blockIdx.x;
  int tid = threadIdx.x;
  floatx4 xv = ((const floatx4*)(x + (size_t)t * HH))[tid];
  ushort4 xo;
  xo.x = f2bf(xv.x); xo.y = f2bf(xv.y); xo.z = f2bf(xv.z); xo.w = f2bf(xv.w);
  ((ushort4*)(xb + (size_t)t * HH))[tid] = xo;

  float part[EE];
#pragma unroll
  for (int e = 0; e < EE; e++) {
    floatx4 g = ((const floatx4*)(gw + e * HH))[tid];
    part[e] = xv.x * g.x + xv.y * g.y + xv.z * g.z + xv.w * g.w;
  }
#pragma unroll
  for (int e = 0; e < EE; e++) {
    float v = part[e];
#pragma unroll
    for (int off = 32; off > 0; off >>= 1) v += __shfl_down(v, off, 64);
    part[e] = v;
  }
  __shared__ float red[4][EE];
  int wave = tid >> 6;
  if ((tid & 63) == 0) {
#pragma unroll
    for (int e = 0; e < EE; e++) red[wave][e] = part[e];
  }
  __syncthreads();
  if (tid == 0) {
    float lg[EE];
#pragma unroll
    for (int e = 0; e < EE; e++)
      lg[e] = red[0][e] + red[1][e] + red[2][e] + red[3][e];
    int e0 = 0;
#pragma unroll
    for (int e = 1; e < EE; e++) if (lg[e] > lg[e0]) e0 = e;
    int e1 = (e0 == 0) ? 1 : 0;
#pragma unroll
    for (int e = 0; e < EE; e++) if (e != e0 && lg[e] > lg[e1]) e1 = e;
    float w0 = 1.f / (1.f + expf(lg[e1] - lg[e0]));
    sel_e[t * 2] = e0; sel_e[t * 2 + 1] = e1;
    sel_w[t * 2] = w0; sel_w[t * 2 + 1] = 1.f - w0;
    atomicAdd(&counts[e0], 1);
    atomicAdd(&counts[e1], 1);
  }
}

// ---------------- exclusive scan of 8 expert counts -------------------------
__global__ void k_scan(const int* __restrict__ counts, int* __restrict__ bases) {
  if (threadIdx.x == 0 && blockIdx.x == 0) {
    int s = 0;
    for (int e = 0; e < EE; e++) { bases[e] = s; s += counts[e]; }
  }
}

// ---------------- fill per-expert row lists ---------------------------------
__global__ __launch_bounds__(256) void k_fill(
    const int* __restrict__ sel_e, const float* __restrict__ sel_w,
    const int* __restrict__ bases, int* __restrict__ cnt2,
    int* __restrict__ row_token, float* __restrict__ row_w) {
  int p = blockIdx.x * 256 + threadIdx.x;
  if (p >= TT * 2) return;
  int e = sel_e[p];
  int slot = bases[e] + atomicAdd(&cnt2[e], 1);
  row_token[slot] = p >> 1;
  row_w[slot] = sel_w[p];
}

// ---------------- weight conversion fp32 -> bf16 ----------------------------
__global__ __launch_bounds__(256) void k_convert(
    const float* __restrict__ w1, const float* __restrict__ w2,
    unsigned short* __restrict__ w1b, unsigned short* __restrict__ w2b) {
  const size_t N1 = (size_t)EE * II * HH;
  size_t i = ((size_t)blockIdx.x * 256 + threadIdx.x) * 4;
  const size_t stride = (size_t)gridDim.x * 256 * 4;
  for (; i < 2 * N1; i += stride) {
    const float* s; unsigned short* d; size_t j;
    if (i < N1) { s = w1; d = w1b; j = i; } else { s = w2; d = w2b; j = i - N1; }
    floatx4 v = *(const floatx4*)(s + j);
    ushort4 o;
    o.x = f2bf(v.x); o.y = f2bf(v.y); o.z = f2bf(v.z); o.w = f2bf(v.w);
    *(ushort4*)(d + j) = o;
  }
}

// ---------------- GEMM1: hid = silu(x @ w1^T), per-expert gathered rows -----
__global__ __launch_bounds__(256) void k_gemm1(
    const unsigned short* __restrict__ xb,
    const unsigned short* __restrict__ w1b,
    unsigned short* __restrict__ hid,
    const int* __restrict__ counts, const int* __restrict__ bases,
    const int* __restrict__ row_token) {
  const int e = blockIdx.z;
  const int count = counts[e];
  const int m0 = blockIdx.y * 128;
  if (m0 >= count) return;
  const int n0 = blockIdx.x * 128;
  const int base = bases[e];

  __shared__ __align__(16) unsigned short As[128 * 32];
  __shared__ __align__(16) unsigned short Bs[128 * 32];

  const int tid = threadIdx.x;
  const int lane = tid & 63;
  const int wave = tid >> 6;
  const int wm = (wave & 1) * 64;
  const int wn = (wave >> 1) * 64;
  const int quad = lane >> 4;
  const int l16 = lane & 15;

  const int rA0 = tid >> 2;       // rows 0..63
  const int rA1 = rA0 + 64;       // rows 64..127
  const int cc = (tid & 3) * 8;   // element col offset (8 bf16 = 16B chunk)

  int g0 = m0 + rA0; if (g0 > count - 1) g0 = count - 1;
  int g1 = m0 + rA1; if (g1 > count - 1) g1 = count - 1;
  const unsigned short* aS0 = xb + (size_t)row_token[base + g0] * HH + cc;
  const unsigned short* aS1 = xb + (size_t)row_token[base + g1] * HH + cc;
  const unsigned short* wp = w1b + (size_t)e * II * HH;
  const unsigned short* bS0 = wp + (size_t)(n0 + rA0) * HH + cc;
  const unsigned short* bS1 = wp + (size_t)(n0 + rA1) * HH + cc;

  unsigned short* lA0 = As + tid * 8;
  unsigned short* lA1 = As + tid * 8 + 2048;
  unsigned short* lB0 = Bs + tid * 8;
  unsigned short* lB1 = Bs + tid * 8 + 2048;

  const floatx4 fz = {0.f, 0.f, 0.f, 0.f};
  floatx4 acc[4][4];
#pragma unroll
  for (int i = 0; i < 4; i++)
#pragma unroll
    for (int j = 0; j < 4; j++) acc[i][j] = fz;

  for (int k0 = 0; k0 < HH; k0 += 32) {
    async_ld16(aS0 + k0, lA0);
    async_ld16(aS1 + k0, lA1);
    async_ld16(bS0 + k0, lB0);
    async_ld16(bS1 + k0, lB1);
    __syncthreads();
    bf16x8 af[4], bfr[4];
#pragma unroll
    for (int i = 0; i < 4; i++) {
      af[i]  = *(const bf16x8*)(As + (wm + i * 16 + l16) * 32 + quad * 8);
      bfr[i] = *(const bf16x8*)(Bs + (wn + i * 16 + l16) * 32 + quad * 8);
    }
#pragma unroll
    for (int i = 0; i < 4; i++)
#pragma unroll
      for (int j = 0; j < 4; j++)
        acc[i][j] = __builtin_amdgcn_mfma_f32_16x16x32_bf16(af[i], bfr[j], acc[i][j], 0, 0, 0);
    __syncthreads();
  }

#pragma unroll
  for (int i = 0; i < 4; i++) {
#pragma unroll
    for (int r = 0; r < 4; r++) {
      const int m = wm + i * 16 + quad * 4 + r;
      if (m0 + m < count) {
        unsigned short* hp = hid + (size_t)(base + m0 + m) * II + n0 + wn + l16;
#pragma unroll
        for (int j = 0; j < 4; j++) {
          float z = acc[i][j][r];
          float s = z / (1.f + __expf(-z));
          hp[j * 16] = f2bf(s);
        }
      }
    }
  }
}

// ---------------- GEMM2: out[token] += w * (hid @ w2^T), split-K=2 ----------
__global__ __launch_bounds__(256) void k_gemm2(
    const unsigned short* __restrict__ hid,
    const unsigned short* __restrict__ w2b,
    float* __restrict__ out,
    const int* __restrict__ counts, const int* __restrict__ bases,
    const int* __restrict__ row_token, const float* __restrict__ row_w) {
  const int e = blockIdx.z;
  const int count = counts[e];
  const int m0 = blockIdx.y * 128;
  if (m0 >= count) return;
  const int nt = blockIdx.x & 7;
  const int ks = blockIdx.x >> 3;
  const int n0 = nt * 128;
  const int base = bases[e];

  __shared__ __align__(16) unsigned short As[128 * 32];
  __shared__ __align__(16) unsigned short Bs[128 * 32];

  const int tid = threadIdx.x;
  const int lane = tid & 63;
  const int wave = tid >> 6;
  const int wm = (wave & 1) * 64;
  const int wn = (wave >> 1) * 64;
  const int quad = lane >> 4;
  const int l16 = lane & 15;

  const int rA0 = tid >> 2;
  const int rA1 = rA0 + 64;
  const int cc = (tid & 3) * 8;

  int g0 = m0 + rA0; if (g0 > count - 1) g0 = count - 1;
  int g1 = m0 + rA1; if (g1 > count - 1) g1 = count - 1;
  const unsigned short* aS0 = hid + (size_t)(base + g0) * II + cc;
  const unsigned short* aS1 = hid + (size_t)(base + g1) * II + cc;
  const unsigned short* wp = w2b + (size_t)e * HH * II;
  const unsigned short* bS0 = wp + (size_t)(n0 + rA0) * II + cc;
  const unsigned short* bS1 = wp + (size_t)(n0 + rA1) * II + cc;

  unsigned short* lA0 = As + tid * 8;
  unsigned short* lA1 = As + tid * 8 + 2048;
  unsigned short* lB0 = Bs + tid * 8;
  unsigned short* lB1 = Bs + tid * 8 + 2048;

  const floatx4 fz = {0.f, 0.f, 0.f, 0.f};
  floatx4 acc[4][4];
#pragma unroll
  for (int i = 0; i < 4; i++)
#pragma unroll
    for (int j = 0; j < 4; j++) acc[i][j] = fz;

  const int kbeg = ks * (II / 2);
  const int kend = kbeg + II / 2;
  for (int k0 = kbeg; k0 < kend; k0 += 32) {
    async_ld16(aS0 + k0, lA0);
    async_ld16(aS1 + k0, lA1);
    async_ld16(bS0 + k0, lB0);
    async_ld16(bS1 + k0, lB1);
    __syncthreads();
    bf16x8 af[4], bfr[4];
#pragma unroll
    for (int i = 0; i < 4; i++) {
      af[i]  = *(const bf16x8*)(As + (wm + i * 16 + l16) * 32 + quad * 8);
      bfr[i] = *(const bf16x8*)(Bs + (wn + i * 16 + l16) * 32 + quad * 8);
    }
#pragma unroll
    for (int i = 0; i < 4; i++)
#pragma unroll
      for (int j = 0; j < 4; j++)
        acc[i][j] = __builtin_amdgcn_mfma_f32_16x16x32_bf16(af[i], bfr[j], acc[i][j], 0, 0, 0);
    __syncthreads();
  }

#pragma unroll
  for (int i = 0; i < 4; i++) {
#pragma unroll
    for (int r = 0; r < 4; r++) {
      const int m = wm + i * 16 + quad * 4 + r;
      if (m0 + m < count) {
        const int row = base + m0 + m;
        const float wgt = row_w[row];
        float* op = out + (size_t)row_token[row] * HH + n0 + wn + l16;
#pragma unroll
        for (int j = 0; j < 4; j++) atomicAdd(op + j * 16, wgt * acc[i][j][r]);
      }
    }
  }
}

// ---------------- launch ----------------------------------------------------
extern "C" void kernel_launch(void* const* d_in, const int* in_sizes, int n_in,
                              void* d_out, int out_size, void* d_ws, size_t ws_size,
                              hipStream_t stream) {
  const float* x  = (const float*)d_in[0];
  const float* gw = (const float*)d_in[1];
  const float* w1 = (const float*)d_in[2];
  const float* w2 = (const float*)d_in[3];
  float* out = (float*)d_out;

  char* ws = (char*)d_ws;
  size_t off = 0;
  auto take = [&](size_t n) -> char* {
    char* p = ws + off;
    off += (n + 255) & ~(size_t)255;
    return p;
  };
  unsigned short* xb  = (unsigned short*)take((size_t)TT * HH * 2);
  unsigned short* w1b = (unsigned short*)take((size_t)EE * II * HH * 2);
  unsigned short* w2b = (unsigned short*)take((size_t)EE * HH * II * 2);
  unsigned short* hid = (unsigned short*)take((size_t)TT * 2 * II * 2);
  int*   counts    = (int*)take(EE * 4);
  int*   cnt2      = (int*)take(EE * 4);
  int*   bases     = (int*)take(EE * 4);
  int*   row_token = (int*)take((size_t)TT * 2 * 4);
  float* row_w     = (float*)take((size_t)TT * 2 * 4);
  int*   sel_e     = (int*)take((size_t)TT * 2 * 4);
  float* sel_w     = (float*)take((size_t)TT * 2 * 4);
  if (off > ws_size) return;  // workspace too small — fail loudly via absmax

  hipMemsetAsync(counts, 0, 512, stream);                    // counts + cnt2
  hipMemsetAsync(out, 0, (size_t)TT * HH * 4, stream);

  k_gating<<<TT, 256, 0, stream>>>(x, gw, xb, sel_e, sel_w, counts);
  k_scan<<<1, 64, 0, stream>>>(counts, bases);
  k_fill<<<(TT * 2) / 256, 256, 0, stream>>>(sel_e, sel_w, bases, cnt2, row_token, row_w);
  k_convert<<<8192, 256, 0, stream>>>(w1, w2, w1b, w2b);
  k_gemm1<<<dim3(II / 128, 16, EE), 256, 0, stream>>>(xb, w1b, hid, counts, bases, row_token);
  k_gemm2<<<dim3(16, 16, EE), 256, 0, stream>>>(hid, w2b, out, counts, bases, row_token, row_w);
}